// Round 3
// baseline (199.946 us; speedup 1.0000x reference)
//
#include <hip/hip_runtime.h>
#include <hip/hip_bf16.h>
#include <math.h>

#define N_NODES 50000
#define N_EDGES 800000
#define C 64
#define EPS_F 1.000001f

// ---- round-17: two-pass scatter role (kill the spill) ----
// Round-16 evidence: VGPR_Count=32 but the scatter role held lo[16]+bk[16]
// across two barriers -> compiler spilled to scratch; each edge iteration
// carried a scratch store+reload on top of its two dependent ssl/stl
// gathers -> latency-serialized straggler blocks (occupancy 38%, nothing
// saturated). Fix: pass A reads ONLY i (coalesced) for the histogram;
// pass C re-reads i,j,v (L2-hot) and recomputes alpha once, bit-identical.
// No per-thread state crosses a barrier -> no spill, full MLP.
#define CAPN 48
#define OVF_IDX 0                     // cnt[0] = global overflow cursor
#define OMAX 4096
#define LOVF 64                       // block-local bucket-spill capacity

#define RB_BITS 7
#define RBUK (1 << RB_BITS)                   // 128 buckets per region
#define NBUCK (2 * N_NODES)                   // 100000 buckets
#define NREG ((NBUCK + RBUK - 1) >> RB_BITS)  // 782 regions (last partial)
#define RCAP 2560                             // lambda=2048, +11sigma
#define EPB 8192                              // edges per scatter block
#define NP1 ((2 * N_EDGES + EPB - 1) / EPB)   // 196 scatter blocks
#define NPREB 784                             // pre blocks (64 rows @512 thr)
#define NK1 (NP1 + NPREB)                     // 980; b<NP1 -> scatter role

#define ZERON (1 + NREG)              // ovf cursor + region cursors

#define NPRE ((N_NODES + 31) / 32)    // 1563 blocks, 32 rows each (K0)

typedef __attribute__((ext_vector_type(8))) unsigned short u16x8;

__device__ __forceinline__ unsigned short f2bf(float f) {
    unsigned u = __float_as_uint(f);
    return (unsigned short)((u + 0x7FFFu + ((u >> 16) & 1u)) >> 16);
}
__device__ __forceinline__ float bf2f(unsigned short b) {
    return __uint_as_float(((unsigned)b) << 16);
}

// ---------------------------------------------------------------------------
// Kernel 0: attention scalars via the wa-trick + zero cursors.
// s_src = (x @ W) @ a_src = x @ (W @ a_src)
// ---------------------------------------------------------------------------
__global__ __launch_bounds__(256) void s_kernel(
    const float* __restrict__ x,
    const float* __restrict__ w_l, const float* __restrict__ a_l,
    const float* __restrict__ w_u, const float* __restrict__ a_u,
    float* __restrict__ ssl, float* __restrict__ stl,
    float* __restrict__ ssu, float* __restrict__ stu,
    int* __restrict__ cnt)
{
    const int b = blockIdx.x;
    const int t = threadIdx.x;

    const int gz = b * 256 + t;
    if (gz < ZERON) cnt[gz] = 0;

    __shared__ float wa[4 * C];      // [l_src | l_tgt | u_src | u_tgt]
    {
        const int v = t >> 6;
        const int k = t & 63;
        const float* __restrict__ w = (v < 2) ? w_l : w_u;
        const float* __restrict__ a = (v < 2) ? a_l : a_u;
        const int ao = (v & 1) * C;
        float acc = 0.f;
#pragma unroll 16
        for (int o = 0; o < C; ++o)
            acc = fmaf(w[k * C + o], a[ao + o], acc);
        wa[v * C + k] = acc;
    }
    __syncthreads();

    const int lane = t & 63;
    const int wv = t >> 6;
    const int row0 = b * 32 + wv * 8;
    if (row0 >= N_NODES) return;

    const float wls = wa[lane], wlt = wa[C + lane];
    const float wus = wa[2 * C + lane], wut = wa[3 * C + lane];

#pragma unroll
    for (int r = 0; r < 8; ++r) {
        const int row = row0 + r;
        if (row >= N_NODES) break;
        const float xv = x[row * C + lane];
        float psl = xv * wls, ptl = xv * wlt;
        float psu = xv * wus, ptu = xv * wut;
#pragma unroll
        for (int o = 32; o >= 1; o >>= 1) {
            psl += __shfl_xor(psl, o);
            ptl += __shfl_xor(ptl, o);
            psu += __shfl_xor(psu, o);
            ptu += __shfl_xor(ptu, o);
        }
        if (lane == 0) {
            ssl[row] = psl; stl[row] = ptl;
            ssu[row] = psu; stu[row] = ptu;
        }
    }
}

// ---------------------------------------------------------------------------
// Kernel 1 (fused): GEMM precompute + pass-1 region scatter (two-pass).
// Scatter role (b < NP1): 8192 edges/block.
//   pass A: load i only (coalesced), LDS histogram over 782 regions.
//   pass B: one atomicAdd(&rcur[region], count) per non-empty region.
//   pass C: re-load i,j,v (L2-hot), gathers + alpha (identical arithmetic),
//           LDS-atomic slot, 8B store into the region chunk.
// Pre role: 8 waves x 8 rows, wave-uniform row ptrs -> scalar x loads.
// ---------------------------------------------------------------------------
__global__ __launch_bounds__(512, 4) void gemm_scatter_kernel(
    const float* __restrict__ x,
    const float* __restrict__ w_l, const float* __restrict__ w_u,
    const float* __restrict__ w_lin,
    const int* __restrict__ lidx, const float* __restrict__ lval,
    const int* __restrict__ uidx, const float* __restrict__ uval,
    const float* __restrict__ ssl, const float* __restrict__ stl,
    const float* __restrict__ ssu, const float* __restrict__ stu,
    unsigned short* __restrict__ xm_l, unsigned short* __restrict__ xm_u,
    float* __restrict__ xlin,
    int* __restrict__ cnt, uint2* __restrict__ rbuf, int2* __restrict__ ovf)
{
    const int b = blockIdx.x, t = threadIdx.x;
    __shared__ int hist[NREG];        // 3.1 KB; count -> base/cursor in place

    if (b < NP1) {
        // ---- pass-1 scatter role ----
        const int p = b;
        int* __restrict__ rcur = cnt + 1;

        for (int s0 = t; s0 < NREG; s0 += 512) hist[s0] = 0;
        __syncthreads();

        const int gbase = p * EPB + t;

        // pass A: histogram only (single coalesced i-load per edge)
#pragma unroll 4
        for (int k = 0; k < 16; ++k) {
            const int g = gbase + k * 512;
            if (g < 2 * N_EDGES) {
                const int bk = (g < N_EDGES) ? (2 * lidx[g])
                                             : (2 * uidx[g - N_EDGES] + 1);
                atomicAdd(&hist[bk >> RB_BITS], 1);
            }
        }
        __syncthreads();

        for (int cb = t; cb < NREG; cb += 512) {
            const int c = hist[cb];
            hist[cb] = c ? atomicAdd(&rcur[cb], c) : 0;   // count -> global base
        }
        __syncthreads();

        // pass C: recompute + place (no state crossed the barriers)
#pragma unroll 4
        for (int k = 0; k < 16; ++k) {
            const int g = gbase + k * 512;
            if (g < 2 * N_EDGES) {
                int i, j, bk;
                float v, s;
                if (g < N_EDGES) {
                    i = lidx[g]; j = lidx[N_EDGES + g]; v = lval[g];
                    s = ssl[j] + stl[i];
                    bk = 2 * i;
                } else {
                    const int e = g - N_EDGES;
                    i = uidx[e]; j = uidx[N_EDGES + e]; v = uval[e];
                    s = ssu[j] + stu[i];
                    bk = 2 * i + 1;
                }
                s = (s > 0.f) ? s : expm1f(s);
                const unsigned lo = ((unsigned)j << 16) | (unsigned)f2bf(s * v);
                const int cb = bk >> RB_BITS;
                const int slot = atomicAdd(&hist[cb], 1); // global slot in region
                if (slot < RCAP) {
                    rbuf[(size_t)cb * RCAP + slot] = make_uint2(lo, (unsigned)bk);
                } else {
                    const int oi = atomicAdd(&cnt[OVF_IDX], 1);
                    if (oi < OMAX) ovf[oi] = make_int2(bk, (int)lo);
                }
            }
        }
        return;
    }

    // ---- pre role: rows pid*64 .. +63 (8 waves x 8 rows) ----
    const int pid = b - NP1;
    const int lane = t & 63;
    const int wvu = __builtin_amdgcn_readfirstlane(t >> 6);
    const int row0 = pid * 64 + wvu * 8;
    if (row0 >= N_NODES) return;

    const float* xr[8];
#pragma unroll
    for (int r = 0; r < 8; ++r) {
        int rr = row0 + r;
        if (rr >= N_NODES) rr = N_NODES - 1;
        xr[r] = x + (size_t)rr * C;
    }

    float acc_l[8] = {0,0,0,0,0,0,0,0};
    float acc_u[8] = {0,0,0,0,0,0,0,0};
    float acc_n[8] = {0,0,0,0,0,0,0,0};

#pragma unroll 1
    for (int kc = 0; kc < C; kc += 4) {
#pragma unroll
        for (int kk = 0; kk < 4; ++kk) {
            const int k = kc + kk;
            const float wl = w_l[k * C + lane];
            const float wu = w_u[k * C + lane];
            const float wn = w_lin[k * C + lane];
#pragma unroll
            for (int r = 0; r < 8; ++r) {
                const float xk = xr[r][k];      // wave-uniform -> scalar load
                acc_l[r] = fmaf(xk, wl, acc_l[r]);
                acc_u[r] = fmaf(xk, wu, acc_u[r]);
                acc_n[r] = fmaf(xk, wn, acc_n[r]);
            }
        }
    }

#pragma unroll
    for (int r = 0; r < 8; ++r) {
        const int row = row0 + r;
        if (row < N_NODES) {
            xm_l[row * C + lane] = f2bf(acc_l[r]);
            xm_u[row * C + lane] = f2bf(acc_u[r]);
            xlin[row * C + lane] = acc_n[r] * EPS_F;
        }
    }
}

// ---------------------------------------------------------------------------
// Kernel 2: gather v9 — one block per REGION (64 nodes x 2 convs).
// Phase 1: coalesced read of the region's dense chunk, LDS-atomic sort into
//          128 LDS lists (CAPN slots each); bucket spills -> local LDS list.
// Phase 2: 8 waves x 8 nodes; per node the conv-0/conv-1 LDS lists walked
//          with interleaved cursors; batch of 8: sub8=lane>>3 picks record
//          (LDS broadcast read), cg=lane&7 picks 8 channels (16 B u16x8 xm
//          row load). Register accumulation, xor-shuffle reduce, direct
//          lane<8 float4 stores (256 B contiguous per node) + xlin + ReLU.
// ---------------------------------------------------------------------------
__global__ __launch_bounds__(512) void gather_kernel(
    const float* __restrict__ xlin,
    const int* __restrict__ cnt, const uint2* __restrict__ rbuf,
    const int2* __restrict__ ovf,
    const unsigned short* __restrict__ xm_l, const unsigned short* __restrict__ xm_u,
    float* __restrict__ out)
{
    const int cb = blockIdx.x;
    const int t = threadIdx.x;
    const int wv = t >> 6, lane = t & 63;
    const int sub8 = lane >> 3;
    const int cg = lane & 7;

    __shared__ unsigned lists[RBUK * CAPN];  // 24.6 KB
    __shared__ int cur[RBUK];
    __shared__ int lovf_bk[LOVF];
    __shared__ unsigned lovf_rc[LOVF];
    __shared__ int lc;

    for (int s0 = t; s0 < RBUK; s0 += 512) cur[s0] = 0;
    if (t == 0) lc = 0;
    __syncthreads();

    // ---- phase 1: distribute region chunk into LDS lists ----
    const int n = min(cnt[1 + cb], RCAP);
    const uint2* __restrict__ rb = rbuf + (size_t)cb * RCAP;
    for (int r = t; r < n; r += 512) {
        const uint2 e = rb[r];
        const int local = (int)e.y & (RBUK - 1);
        const int rank = atomicAdd(&cur[local], 1);
        if (rank < CAPN) {
            lists[local * CAPN + rank] = e.x;
        } else {
            const int o = atomicAdd(&lc, 1);
            if (o < LOVF) { lovf_bk[o] = local; lovf_rc[o] = e.x; }
        }
    }
    __syncthreads();

    const int oc = min(cnt[OVF_IDX], OMAX);
    const int lc2 = min(lc, LOVF);

    // ---- phase 2: per-node interleaved walk out of LDS ----
#pragma unroll 1
    for (int p = 0; p < 8; ++p) {
        const int q = wv * 8 + p;
        const int node = cb * 64 + q;
        if (node >= N_NODES) break;
        const int lA = 2 * q, lB = 2 * q + 1;
        const int lenA = min(cur[lA], CAPN);
        const int lenB = min(cur[lB], CAPN);
        const unsigned* __restrict__ lstA = lists + lA * CAPN;
        const unsigned* __restrict__ lstB = lists + lB * CAPN;

        float acc[8] = {0.f,0.f,0.f,0.f,0.f,0.f,0.f,0.f};
        int kA = 0, kB = 0;
        while ((kA < lenA) | (kB < lenB)) {
            const int iA = kA + sub8, iB = kB + sub8;
            const bool aA = iA < lenA, aB = iB < lenB;
            const unsigned rwA = lstA[aA ? iA : kA];
            const unsigned rwB = lstB[aB ? iB : kB];
            const int jA = aA ? (int)(rwA >> 16) : 0;
            const int jB = aB ? (int)(rwB >> 16) : 0;
            const float wA = aA ? bf2f((unsigned short)(rwA & 0xFFFFu)) : 0.f;
            const float wB = aB ? bf2f((unsigned short)(rwB & 0xFFFFu)) : 0.f;
            const u16x8 rowA = *(const u16x8*)(xm_l + jA * C + cg * 8);
            const u16x8 rowB = *(const u16x8*)(xm_u + jB * C + cg * 8);
#pragma unroll
            for (int c = 0; c < 8; ++c)
                acc[c] = fmaf(wA, bf2f(rowA[c]), acc[c]);
#pragma unroll
            for (int c = 0; c < 8; ++c)
                acc[c] = fmaf(wB, bf2f(rowB[c]), acc[c]);
            kA += (kA < lenA) ? 8 : 0;
            kB += (kB < lenB) ? 8 : 0;
        }

        // global (region-spill) overflow tail — expected empty
        for (int u = 0; u < oc; ++u) {
            const int2 e = ovf[u];
            if (e.x == 2 * node || e.x == 2 * node + 1) {
                const unsigned rw = (unsigned)e.y;
                const int j = (int)(rw >> 16);
                const float w = (sub8 == 0) ? bf2f((unsigned short)(rw & 0xFFFFu)) : 0.f;
                const unsigned short* xm = (e.x & 1) ? xm_u : xm_l;
                const u16x8 row = *(const u16x8*)(xm + j * C + cg * 8);
#pragma unroll
                for (int c = 0; c < 8; ++c)
                    acc[c] = fmaf(w, bf2f(row[c]), acc[c]);
            }
        }

        // local (bucket-spill) overflow tail — expected empty
        for (int u = 0; u < lc2; ++u) {
            const int bkl = lovf_bk[u];
            if (bkl == lA || bkl == lB) {
                const unsigned rw = lovf_rc[u];
                const int j = (int)(rw >> 16);
                const float w = (sub8 == 0) ? bf2f((unsigned short)(rw & 0xFFFFu)) : 0.f;
                const unsigned short* xm = (bkl & 1) ? xm_u : xm_l;
                const u16x8 row = *(const u16x8*)(xm + j * C + cg * 8);
#pragma unroll
                for (int c = 0; c < 8; ++c)
                    acc[c] = fmaf(w, bf2f(row[c]), acc[c]);
            }
        }

        // reduce over the 8 record slots (lane bits 3..5)
#pragma unroll
        for (int o = 8; o <= 32; o <<= 1)
#pragma unroll
            for (int c = 0; c < 8; ++c)
                acc[c] += __shfl_xor(acc[c], o);

        if (lane < 8) {
            const float* __restrict__ xl = xlin + (size_t)node * C + lane * 8;
            const float4 xa = *(const float4*)(xl);
            const float4 xb = *(const float4*)(xl + 4);
            float4 oa, ob;
            oa.x = fmaxf(acc[0] + xa.x, 0.f);
            oa.y = fmaxf(acc[1] + xa.y, 0.f);
            oa.z = fmaxf(acc[2] + xa.z, 0.f);
            oa.w = fmaxf(acc[3] + xa.w, 0.f);
            ob.x = fmaxf(acc[4] + xb.x, 0.f);
            ob.y = fmaxf(acc[5] + xb.y, 0.f);
            ob.z = fmaxf(acc[6] + xb.z, 0.f);
            ob.w = fmaxf(acc[7] + xb.w, 0.f);
            float* __restrict__ op = out + (size_t)node * C + lane * 8;
            *(float4*)(op) = oa;
            *(float4*)(op + 4) = ob;
        }
    }
}

extern "C" void kernel_launch(void* const* d_in, const int* in_sizes, int n_in,
                              void* d_out, int out_size, void* d_ws, size_t ws_size,
                              hipStream_t stream)
{
    const float* x          = (const float*)d_in[0];
    const int*   lower_idx  = (const int*)d_in[1];
    const float* lower_vals = (const float*)d_in[2];
    const int*   upper_idx  = (const int*)d_in[3];
    const float* upper_vals = (const float*)d_in[4];
    const float* w_lower    = (const float*)d_in[5];
    const float* a_lower    = (const float*)d_in[6];
    const float* w_upper    = (const float*)d_in[7];
    const float* a_upper    = (const float*)d_in[8];
    const float* w_lin      = (const float*)d_in[9];

    float* out = (float*)d_out;
    char* ws = (char*)d_ws;

    // ---- workspace layout (~43 MB) ----
    const size_t NC_F = (size_t)N_NODES * C * sizeof(float);
    const size_t NC_H = (size_t)N_NODES * C * sizeof(unsigned short);
    unsigned short* xm_l = (unsigned short*)ws;  ws += NC_H;
    unsigned short* xm_u = (unsigned short*)ws;  ws += NC_H;
    float* xlin = (float*)ws;                 ws += NC_F;
    float* ssl  = (float*)ws;                 ws += N_NODES * sizeof(float);
    float* stl  = (float*)ws;                 ws += N_NODES * sizeof(float);
    float* ssu  = (float*)ws;                 ws += N_NODES * sizeof(float);
    float* stu  = (float*)ws;                 ws += N_NODES * sizeof(float);
    int2* ovf   = (int2*)ws;                  ws += OMAX * sizeof(int2);
    uint2* rbuf = (uint2*)ws;                 ws += (size_t)NREG * RCAP * sizeof(uint2); // 16.0 MB
    int* cnt    = (int*)ws;                   ws += (size_t)(ZERON + 32) * sizeof(int);

    // K0: attention scalars (wa-trick) + cursor zeroing (ovf + region)
    s_kernel<<<NPRE, 256, 0, stream>>>(
        x, w_lower, a_lower, w_upper, a_upper,
        ssl, stl, ssu, stu, cnt);

    // K1: fused GEMM precompute + pass-1 region scatter (two-pass)
    gemm_scatter_kernel<<<NK1, 512, 0, stream>>>(
        x, w_lower, w_upper, w_lin,
        lower_idx, lower_vals, upper_idx, upper_vals,
        ssl, stl, ssu, stu,
        xm_l, xm_u, xlin, cnt, rbuf, ovf);

    // K2: gather v9 (region-resident distribute + walk) + skip + relu
    gather_kernel<<<NREG, 512, 0, stream>>>(
        xlin, cnt, rbuf, ovf, xm_l, xm_u, out);
}

// Round 4
// 174.523 us; speedup vs baseline: 1.1457x; 1.1457x over previous
//
#include <hip/hip_runtime.h>
#include <hip/hip_bf16.h>
#include <math.h>

#define N_NODES 50000
#define N_EDGES 800000
#define C 64
#define EPS_F 1.000001f

// ---- round-18: defer alpha to gather; fuse s-computation into pre role ----
// Round-17 post-mortem: round-16's lo[16]/bk[16] lived in the unified
// VGPR/AGPR file (no scratch) -> the two-pass "fix" only added work and
// stretched the rbuf dirty-line window (+30 MB writebacks = +30 us).
// Reverted to the single-pass scatter. New: records carry {j | bf16(v)}
// instead of {j | bf16(alpha)} -> scatter needs NO ssl/stl gathers and no
// expm1 (only coalesced edge reads), and s_kernel's only consumer moves to
// gather (alpha = elu(ssl[j]+stl[node])*v, ssl tables are 200 KB L2-hot).
// s-values are computed in the pre role from the f32 accumulators
// (s_src = xm_row . a[:64], 4 shuffle-reduce dots per row) -> s_kernel and
// its kernel boundary deleted; cursor zeroing via one 3 KB hipMemsetAsync.
#define CAPN 48
#define OVF_IDX 0                     // cnt[0] = global overflow cursor
#define OMAX 4096
#define LOVF 64                       // block-local bucket-spill capacity

#define RB_BITS 7
#define RBUK (1 << RB_BITS)                   // 128 buckets per region
#define NBUCK (2 * N_NODES)                   // 100000 buckets
#define NREG ((NBUCK + RBUK - 1) >> RB_BITS)  // 782 regions (last partial)
#define RCAP 2560                             // lambda=2048, +11sigma
#define EPB 8192                              // edges per scatter block
#define NP1 ((2 * N_EDGES + EPB - 1) / EPB)   // 196 scatter blocks
#define NPREB 784                             // pre blocks (64 rows @512 thr)
#define NK1 (NP1 + NPREB)                     // 980; b%5==0 -> scatter role

#define ZERON (1 + NREG)              // ovf cursor + region cursors

typedef __attribute__((ext_vector_type(8))) unsigned short u16x8;

__device__ __forceinline__ unsigned short f2bf(float f) {
    unsigned u = __float_as_uint(f);
    return (unsigned short)((u + 0x7FFFu + ((u >> 16) & 1u)) >> 16);
}
__device__ __forceinline__ float bf2f(unsigned short b) {
    return __uint_as_float(((unsigned)b) << 16);
}

// ---------------------------------------------------------------------------
// Kernel 1 (fused): GEMM precompute + s-dots + pass-1 region scatter.
// Scatter role (b%5==0): 8192 edges/block, single pass (round-16 form),
//   records {j<<16 | bf16(v)} held in regs/AGPRs across the barriers;
//   NO ssl/stl gathers, NO expm1 -> pure coalesced reads + LDS hist.
// Pre role: 8 waves x 8 rows; f32 GEMM accumulators -> xm_l/xm_u/xlin
//   stores + 4 per-row shuffle-reduce dots with a_l/a_u -> ssl/stl/ssu/stu.
// ---------------------------------------------------------------------------
__global__ __launch_bounds__(512) void gemm_scatter_kernel(
    const float* __restrict__ x,
    const float* __restrict__ w_l, const float* __restrict__ a_l,
    const float* __restrict__ w_u, const float* __restrict__ a_u,
    const float* __restrict__ w_lin,
    const int* __restrict__ lidx, const float* __restrict__ lval,
    const int* __restrict__ uidx, const float* __restrict__ uval,
    unsigned short* __restrict__ xm_l, unsigned short* __restrict__ xm_u,
    float* __restrict__ xlin,
    float* __restrict__ ssl, float* __restrict__ stl,
    float* __restrict__ ssu, float* __restrict__ stu,
    int* __restrict__ cnt, uint2* __restrict__ rbuf, int2* __restrict__ ovf)
{
    const int b = blockIdx.x, t = threadIdx.x;
    __shared__ int hist[NREG];        // 3.1 KB; count -> base/cursor in place

    if (b % 5 == 0) {
        // ---- pass-1 scatter role (single-pass, round-16 form) ----
        const int p = b / 5;
        int* __restrict__ rcur = cnt + 1;

        for (int s0 = t; s0 < NREG; s0 += 512) hist[s0] = 0;
        __syncthreads();

        unsigned lo[16];
        int bk[16];
        const int gbase = p * EPB + t;
#pragma unroll
        for (int k = 0; k < 16; ++k) {
            const int g = gbase + k * 512;
            bk[k] = -1;
            if (g < 2 * N_EDGES) {
                int i, j;
                float v;
                if (g < N_EDGES) {
                    i = lidx[g]; j = lidx[N_EDGES + g]; v = lval[g];
                    bk[k] = 2 * i;
                } else {
                    const int e = g - N_EDGES;
                    i = uidx[e]; j = uidx[N_EDGES + e]; v = uval[e];
                    bk[k] = 2 * i + 1;
                }
                lo[k] = ((unsigned)j << 16) | (unsigned)f2bf(v);
                atomicAdd(&hist[bk[k] >> RB_BITS], 1);
            }
        }
        __syncthreads();

        for (int cb = t; cb < NREG; cb += 512) {
            const int c = hist[cb];
            hist[cb] = c ? atomicAdd(&rcur[cb], c) : 0;   // count -> global base
        }
        __syncthreads();

#pragma unroll
        for (int k = 0; k < 16; ++k) {
            if (bk[k] >= 0) {
                const int cb = bk[k] >> RB_BITS;
                const int slot = atomicAdd(&hist[cb], 1); // global slot in region
                if (slot < RCAP) {
                    rbuf[(size_t)cb * RCAP + slot] = make_uint2(lo[k], (unsigned)bk[k]);
                } else {
                    const int oi = atomicAdd(&cnt[OVF_IDX], 1);
                    if (oi < OMAX) ovf[oi] = make_int2(bk[k], (int)lo[k]);
                }
            }
        }
        return;
    }

    // ---- pre role: rows pid*64 .. +63 (8 waves x 8 rows) ----
    const int pid = b - b / 5 - 1;
    const int lane = t & 63;
    const int wvu = __builtin_amdgcn_readfirstlane(t >> 6);
    const int row0 = pid * 64 + wvu * 8;
    if (row0 >= N_NODES) return;

    const float* xr[8];
#pragma unroll
    for (int r = 0; r < 8; ++r) {
        int rr = row0 + r;
        if (rr >= N_NODES) rr = N_NODES - 1;
        xr[r] = x + (size_t)rr * C;
    }

    float acc_l[8] = {0,0,0,0,0,0,0,0};
    float acc_u[8] = {0,0,0,0,0,0,0,0};
    float acc_n[8] = {0,0,0,0,0,0,0,0};

#pragma unroll 1
    for (int kc = 0; kc < C; kc += 4) {
#pragma unroll
        for (int kk = 0; kk < 4; ++kk) {
            const int k = kc + kk;
            const float wl = w_l[k * C + lane];
            const float wu = w_u[k * C + lane];
            const float wn = w_lin[k * C + lane];
#pragma unroll
            for (int r = 0; r < 8; ++r) {
                const float xk = xr[r][k];      // wave-uniform -> scalar load
                acc_l[r] = fmaf(xk, wl, acc_l[r]);
                acc_u[r] = fmaf(xk, wu, acc_u[r]);
                acc_n[r] = fmaf(xk, wn, acc_n[r]);
            }
        }
    }

    // a-vectors for the fused s-dots (coalesced, L2-hot)
    const float als = a_l[lane], alt = a_l[C + lane];
    const float aus = a_u[lane], aut = a_u[C + lane];

#pragma unroll
    for (int r = 0; r < 8; ++r) {
        const int row = row0 + r;
        if (row < N_NODES) {
            xm_l[row * C + lane] = f2bf(acc_l[r]);
            xm_u[row * C + lane] = f2bf(acc_u[r]);
            xlin[row * C + lane] = acc_n[r] * EPS_F;

            // s-dots: ssl = xm_l_row . a_l[:64], stl = xm_l_row . a_l[64:],
            //         ssu/stu likewise with a_u (f32 accumulators)
            float psl = acc_l[r] * als, ptl = acc_l[r] * alt;
            float psu = acc_u[r] * aus, ptu = acc_u[r] * aut;
#pragma unroll
            for (int o = 32; o >= 1; o >>= 1) {
                psl += __shfl_xor(psl, o);
                ptl += __shfl_xor(ptl, o);
                psu += __shfl_xor(psu, o);
                ptu += __shfl_xor(ptu, o);
            }
            if (lane == 0) {
                ssl[row] = psl; stl[row] = ptl;
                ssu[row] = psu; stu[row] = ptu;
            }
        }
    }
}

// ---------------------------------------------------------------------------
// Kernel 2: gather v10 — one block per REGION (64 nodes x 2 convs).
// Phase 1: coalesced read of the region's dense chunk, LDS-atomic sort into
//          128 LDS lists; bucket spills -> local LDS list.
// Phase 2: per node, interleaved conv-0/conv-1 walk; records now carry
//          {j | bf16(v)} so alpha = elu(ssl[j] + stl[node]) * v is computed
//          here (ssl/ssu 200 KB L2-resident; stl/stu wave-uniform per node;
//          elu chain overlaps the independent xm row loads).
// ---------------------------------------------------------------------------
__global__ __launch_bounds__(512) void gather_kernel(
    const float* __restrict__ xlin,
    const int* __restrict__ cnt, const uint2* __restrict__ rbuf,
    const int2* __restrict__ ovf,
    const unsigned short* __restrict__ xm_l, const unsigned short* __restrict__ xm_u,
    const float* __restrict__ ssl, const float* __restrict__ stl,
    const float* __restrict__ ssu, const float* __restrict__ stu,
    float* __restrict__ out)
{
    const int cb = blockIdx.x;
    const int t = threadIdx.x;
    const int wv = t >> 6, lane = t & 63;
    const int sub8 = lane >> 3;
    const int cg = lane & 7;

    __shared__ unsigned lists[RBUK * CAPN];  // 24.6 KB
    __shared__ int cur[RBUK];
    __shared__ int lovf_bk[LOVF];
    __shared__ unsigned lovf_rc[LOVF];
    __shared__ int lc;

    for (int s0 = t; s0 < RBUK; s0 += 512) cur[s0] = 0;
    if (t == 0) lc = 0;
    __syncthreads();

    // ---- phase 1: distribute region chunk into LDS lists ----
    const int n = min(cnt[1 + cb], RCAP);
    const uint2* __restrict__ rb = rbuf + (size_t)cb * RCAP;
    for (int r = t; r < n; r += 512) {
        const uint2 e = rb[r];
        const int local = (int)e.y & (RBUK - 1);
        const int rank = atomicAdd(&cur[local], 1);
        if (rank < CAPN) {
            lists[local * CAPN + rank] = e.x;
        } else {
            const int o = atomicAdd(&lc, 1);
            if (o < LOVF) { lovf_bk[o] = local; lovf_rc[o] = e.x; }
        }
    }
    __syncthreads();

    const int oc = min(cnt[OVF_IDX], OMAX);
    const int lc2 = min(lc, LOVF);

    // ---- phase 2: per-node interleaved walk out of LDS ----
#pragma unroll 1
    for (int p = 0; p < 8; ++p) {
        const int q = wv * 8 + p;
        const int node = cb * 64 + q;
        if (node >= N_NODES) break;
        const int lA = 2 * q, lB = 2 * q + 1;
        const int lenA = min(cur[lA], CAPN);
        const int lenB = min(cur[lB], CAPN);
        const unsigned* __restrict__ lstA = lists + lA * CAPN;
        const unsigned* __restrict__ lstB = lists + lB * CAPN;

        const float stlN = stl[node];
        const float stuN = stu[node];

        float acc[8] = {0.f,0.f,0.f,0.f,0.f,0.f,0.f,0.f};
        int kA = 0, kB = 0;
        while ((kA < lenA) | (kB < lenB)) {
            const int iA = kA + sub8, iB = kB + sub8;
            const bool aA = iA < lenA, aB = iB < lenB;
            const unsigned rwA = lstA[aA ? iA : kA];
            const unsigned rwB = lstB[aB ? iB : kB];
            const int jA = aA ? (int)(rwA >> 16) : 0;
            const int jB = aB ? (int)(rwB >> 16) : 0;
            const float vA = aA ? bf2f((unsigned short)(rwA & 0xFFFFu)) : 0.f;
            const float vB = aB ? bf2f((unsigned short)(rwB & 0xFFFFu)) : 0.f;
            // alpha = elu(s_src[j] + s_tgt[i]) * v   (vA=0 kills inactive lanes)
            const float sA = ssl[jA] + stlN;
            const float sB = ssu[jB] + stuN;
            const float eA = (sA > 0.f) ? sA : expm1f(sA);
            const float eB = (sB > 0.f) ? sB : expm1f(sB);
            const float wA = eA * vA;
            const float wB = eB * vB;
            const u16x8 rowA = *(const u16x8*)(xm_l + jA * C + cg * 8);
            const u16x8 rowB = *(const u16x8*)(xm_u + jB * C + cg * 8);
#pragma unroll
            for (int c = 0; c < 8; ++c)
                acc[c] = fmaf(wA, bf2f(rowA[c]), acc[c]);
#pragma unroll
            for (int c = 0; c < 8; ++c)
                acc[c] = fmaf(wB, bf2f(rowB[c]), acc[c]);
            kA += (kA < lenA) ? 8 : 0;
            kB += (kB < lenB) ? 8 : 0;
        }

        // global (region-spill) overflow tail — expected empty
        for (int u = 0; u < oc; ++u) {
            const int2 e = ovf[u];
            if (e.x == 2 * node || e.x == 2 * node + 1) {
                const unsigned rw = (unsigned)e.y;
                const int j = (int)(rw >> 16);
                const float v = bf2f((unsigned short)(rw & 0xFFFFu));
                const int cv = e.x & 1;
                const float s = (cv ? ssu[j] : ssl[j]) + (cv ? stuN : stlN);
                const float el = (s > 0.f) ? s : expm1f(s);
                const float w = (sub8 == 0) ? el * v : 0.f;
                const unsigned short* xm = cv ? xm_u : xm_l;
                const u16x8 row = *(const u16x8*)(xm + j * C + cg * 8);
#pragma unroll
                for (int c = 0; c < 8; ++c)
                    acc[c] = fmaf(w, bf2f(row[c]), acc[c]);
            }
        }

        // local (bucket-spill) overflow tail — expected empty
        for (int u = 0; u < lc2; ++u) {
            const int bkl = lovf_bk[u];
            if (bkl == lA || bkl == lB) {
                const unsigned rw = lovf_rc[u];
                const int j = (int)(rw >> 16);
                const float v = bf2f((unsigned short)(rw & 0xFFFFu));
                const int cv = bkl & 1;
                const float s = (cv ? ssu[j] : ssl[j]) + (cv ? stuN : stlN);
                const float el = (s > 0.f) ? s : expm1f(s);
                const float w = (sub8 == 0) ? el * v : 0.f;
                const unsigned short* xm = cv ? xm_u : xm_l;
                const u16x8 row = *(const u16x8*)(xm + j * C + cg * 8);
#pragma unroll
                for (int c = 0; c < 8; ++c)
                    acc[c] = fmaf(w, bf2f(row[c]), acc[c]);
            }
        }

        // reduce over the 8 record slots (lane bits 3..5)
#pragma unroll
        for (int o = 8; o <= 32; o <<= 1)
#pragma unroll
            for (int c = 0; c < 8; ++c)
                acc[c] += __shfl_xor(acc[c], o);

        if (lane < 8) {
            const float* __restrict__ xl = xlin + (size_t)node * C + lane * 8;
            const float4 xa = *(const float4*)(xl);
            const float4 xb = *(const float4*)(xl + 4);
            float4 oa, ob;
            oa.x = fmaxf(acc[0] + xa.x, 0.f);
            oa.y = fmaxf(acc[1] + xa.y, 0.f);
            oa.z = fmaxf(acc[2] + xa.z, 0.f);
            oa.w = fmaxf(acc[3] + xa.w, 0.f);
            ob.x = fmaxf(acc[4] + xb.x, 0.f);
            ob.y = fmaxf(acc[5] + xb.y, 0.f);
            ob.z = fmaxf(acc[6] + xb.z, 0.f);
            ob.w = fmaxf(acc[7] + xb.w, 0.f);
            float* __restrict__ op = out + (size_t)node * C + lane * 8;
            *(float4*)(op) = oa;
            *(float4*)(op + 4) = ob;
        }
    }
}

extern "C" void kernel_launch(void* const* d_in, const int* in_sizes, int n_in,
                              void* d_out, int out_size, void* d_ws, size_t ws_size,
                              hipStream_t stream)
{
    const float* x          = (const float*)d_in[0];
    const int*   lower_idx  = (const int*)d_in[1];
    const float* lower_vals = (const float*)d_in[2];
    const int*   upper_idx  = (const int*)d_in[3];
    const float* upper_vals = (const float*)d_in[4];
    const float* w_lower    = (const float*)d_in[5];
    const float* a_lower    = (const float*)d_in[6];
    const float* w_upper    = (const float*)d_in[7];
    const float* a_upper    = (const float*)d_in[8];
    const float* w_lin      = (const float*)d_in[9];

    float* out = (float*)d_out;
    char* ws = (char*)d_ws;

    // ---- workspace layout (~43 MB) ----
    const size_t NC_F = (size_t)N_NODES * C * sizeof(float);
    const size_t NC_H = (size_t)N_NODES * C * sizeof(unsigned short);
    unsigned short* xm_l = (unsigned short*)ws;  ws += NC_H;
    unsigned short* xm_u = (unsigned short*)ws;  ws += NC_H;
    float* xlin = (float*)ws;                 ws += NC_F;
    float* ssl  = (float*)ws;                 ws += N_NODES * sizeof(float);
    float* stl  = (float*)ws;                 ws += N_NODES * sizeof(float);
    float* ssu  = (float*)ws;                 ws += N_NODES * sizeof(float);
    float* stu  = (float*)ws;                 ws += N_NODES * sizeof(float);
    int2* ovf   = (int2*)ws;                  ws += OMAX * sizeof(int2);
    uint2* rbuf = (uint2*)ws;                 ws += (size_t)NREG * RCAP * sizeof(uint2); // 16.0 MB
    int* cnt    = (int*)ws;                   ws += (size_t)(ZERON + 32) * sizeof(int);

    // K0: zero cursors (ovf + region) — 3.1 KB
    hipMemsetAsync(cnt, 0, ZERON * sizeof(int), stream);

    // K1: fused GEMM precompute + s-dots + pass-1 region scatter
    gemm_scatter_kernel<<<NK1, 512, 0, stream>>>(
        x, w_lower, a_lower, w_upper, a_upper, w_lin,
        lower_idx, lower_vals, upper_idx, upper_vals,
        xm_l, xm_u, xlin, ssl, stl, ssu, stu, cnt, rbuf, ovf);

    // K2: gather v10 (region-resident distribute + alpha + walk) + skip + relu
    gather_kernel<<<NREG, 512, 0, stream>>>(
        xlin, cnt, rbuf, ovf, xm_l, xm_u, ssl, stl, ssu, stu, out);
}